// Round 2
// baseline (207.442 us; speedup 1.0000x reference)
//
#include <hip/hip_runtime.h>
#include <hip/hip_bf16.h>
#include <cstdint>
#include <cstddef>

#define B_ROWS 16384
#define D_DIM  256
#define TEMP_INV 14.285714285714286f   // 1/0.07

#define BM 256
#define BN 256

using frag_cd = __attribute__((ext_vector_type(4))) float;   // 4 fp32
using i32x4   = __attribute__((ext_vector_type(4))) int;     // one 16B chunk
using i32x8   = __attribute__((ext_vector_type(8))) int;     // 32B f8f6f4 operand

__device__ __forceinline__ void gld_lds16(const void* g, void* l) {
    __builtin_amdgcn_global_load_lds(
        (const __attribute__((address_space(1))) void*)g,
        (__attribute__((address_space(3))) void*)l,
        16, 0, 0);
}

// ---------------------------------------------------------------------------
// fp8 operand storage layout (R17, verified absmax=0): fragment-major.
// row group g = row>>4, r = row&15; k-byte kappa: kt = kappa>>7,
// chunk c = (kappa&127)>>4, h = c>>2, q = c&3, b = kappa&15.
// byte offset = g*4096 + kt*2048 + h*1024 + q*256 + r*16 + b.
// MFMA 16x16x128 fp8 fragment for lane (quad,l15): chunks c=quad (h0) and
// c=quad+4 (h1) of row l15's kt-slab == slab_base + lane*16 (+1024).
// => staging global->LDS is a LINEAR copy; every ds_read is contiguous 1KB/wave.
// ---------------------------------------------------------------------------

// Kernel 1 (R18): one block per 16-row group; computes L2 norms with 16 lanes/row,
// packs fp8 into fragment-major order via a small LDS buffer, stores the whole
// group's 4KB output as coalesced uint4 (fixes R17's scattered 16B stores).
// Also zero-initializes row_sums/col_sums/out.
__global__ __launch_bounds__(256) void norm_diag_kernel(
    const float* __restrict__ q, const float* __restrict__ d,
    unsigned int* __restrict__ qn, unsigned int* __restrict__ dn,
    float* __restrict__ diag,
    float* __restrict__ row_sums, float* __restrict__ col_sums,
    float* __restrict__ out) {
    const int b = blockIdx.x;   // group index, 0..1023
    if (b < 64)            row_sums[b * 256 + threadIdx.x] = 0.0f;
    else if (b < 128)      col_sums[(b - 64) * 256 + threadIdx.x] = 0.0f;
    else if (b == 128 && threadIdx.x == 0) out[0] = 0.0f;

    const int t    = threadIdx.x;
    const int lane = t & 63;
    const int w    = t >> 6;
    const int l15  = lane & 15;
    const int rw   = lane >> 4;          // row within wave's 4
    const int r    = w * 4 + rw;         // row & 15 (0..15)
    const int row  = b * 16 + r;

    const float4* qr = (const float4*)(q + (size_t)row * D_DIM);
    const float4* dr = (const float4*)(d + (size_t)row * D_DIM);
    float4 qv[4], dv[4];
    float qss = 0.f, dss = 0.f, qd = 0.f;
#pragma unroll
    for (int p = 0; p < 4; ++p) {
        qv[p] = qr[l15 + 16 * p];
        dv[p] = dr[l15 + 16 * p];
        qss += qv[p].x*qv[p].x + qv[p].y*qv[p].y + qv[p].z*qv[p].z + qv[p].w*qv[p].w;
        dss += dv[p].x*dv[p].x + dv[p].y*dv[p].y + dv[p].z*dv[p].z + dv[p].w*dv[p].w;
        qd  += qv[p].x*dv[p].x + qv[p].y*dv[p].y + qv[p].z*dv[p].z + qv[p].w*dv[p].w;
    }
    // reduce over the 16 lanes of this row
#pragma unroll
    for (int off = 1; off < 16; off <<= 1) {
        qss += __shfl_xor(qss, off);
        dss += __shfl_xor(dss, off);
        qd  += __shfl_xor(qd,  off);
    }
    const float qinv = 1.0f / fmaxf(sqrtf(qss), 1e-12f);
    const float dinv = 1.0f / fmaxf(sqrtf(dss), 1e-12f);

    __shared__ unsigned int qbuf[1024], dbuf[1024];
#pragma unroll
    for (int p = 0; p < 4; ++p) {
        const int jw = l15 + 16 * p;     // word index in row, 0..63 (kappa=4*jw)
        int qp = 0, dp = 0;
        qp = __builtin_amdgcn_cvt_pk_fp8_f32(qv[p].x * qinv, qv[p].y * qinv, qp, false);
        qp = __builtin_amdgcn_cvt_pk_fp8_f32(qv[p].z * qinv, qv[p].w * qinv, qp, true);
        dp = __builtin_amdgcn_cvt_pk_fp8_f32(dv[p].x * dinv, dv[p].y * dinv, dp, false);
        dp = __builtin_amdgcn_cvt_pk_fp8_f32(dv[p].z * dinv, dv[p].w * dinv, dp, true);
        // fragment-major word offset within group: kt*512 + h*256 + q*64 + r*4 + wi
        const int c    = (jw & 31) >> 2;
        const int widx = ((jw >> 5) << 9) | ((c >> 2) << 8) | ((c & 3) << 6)
                       | (r << 2) | (jw & 3);
        qbuf[widx] = (unsigned int)qp;
        dbuf[widx] = (unsigned int)dp;
    }
    if (l15 == 0) diag[row] = qd * qinv * dinv * TEMP_INV;
    __syncthreads();
    ((uint4*)qn)[(size_t)b * 256 + t] = ((const uint4*)qbuf)[t];
    ((uint4*)dn)[(size_t)b * 256 + t] = ((const uint4*)dbuf)[t];
}

// Kernel 2 (R18): 256x256 tile, 8 waves (2x4), per-wave 128x64 output.
// Rationale: R17 showed operand delivery (not barriers) is the bound; per-wave
// operand bytes/FLOP shrink 1.5x vs 64x64 waves, bringing the LDS pipe (~74K
// cyc/CU) to parity with MFMA (~71K cyc/CU). Full-K double-buffer: both K-tiles
// staged up front, counted s_waitcnt vmcnt(8) keeps tile-1's loads in flight
// across the first barrier (T4) — no __syncthreads vmcnt(0) drain anywhere.
// LDS layout == fragment-major global layout => staging is a linear copy and
// every fragment ds_read_b128 is a contiguous lane*16 pattern (conflict-free).
__global__ __launch_bounds__(512, 2) void gemm_lse_kernel(
    const unsigned char* __restrict__ qn, const unsigned char* __restrict__ dn,
    float* __restrict__ row_sums, float* __restrict__ col_sums) {
    __shared__ unsigned char lds[2][65536];   // [kt][ A 32KB | B 32KB ]

    const int t    = threadIdx.x;
    const int lane = t & 63;
    const int w    = t >> 6;          // 0..7
    const int l15  = lane & 15;
    const int quad = lane >> 4;
    const int wr   = w >> 2;          // 0..1 : row half (128 rows)
    const int wc   = w & 3;           // 0..3 : col quarter (64 cols)

    // XCD swizzle: 4096 blocks -> 8 XCDs x (8 bx-columns x 64 by-rows)
    const int id  = blockIdx.x;
    const int xcd = id & 7;
    const int j   = id >> 3;
    const int bx  = (xcd << 3) | (j & 7);
    const int by  = j >> 3;
    const int rowBase = by * BM;
    const int colBase = bx * BN;

    const unsigned char* aSrc = qn + ((size_t)(rowBase >> 4) << 12);
    const unsigned char* bSrc = dn + ((size_t)(colBase >> 4) << 12);

    frag_cd acc[8][4];
#pragma unroll
    for (int i = 0; i < 8; ++i)
#pragma unroll
        for (int jj = 0; jj < 4; ++jj)
            acc[i][jj] = (frag_cd){0.0f, 0.0f, 0.0f, 0.0f};

    union OpU { i32x8 v; i32x4 h[2]; };

    // ---- Stage both K-tiles (8 gld_lds per thread per tile; linear copy) ----
#pragma unroll
    for (int kt = 0; kt < 2; ++kt) {
#pragma unroll
        for (int it = 0; it < 4; ++it) {
            const int ci = it * 512 + t;                       // 0..2047
            const int so = ((ci >> 7) << 12) | (kt << 11) | ((ci & 127) << 4);
            gld_lds16(aSrc + so, &lds[kt][ci * 16]);
        }
#pragma unroll
        for (int it = 0; it < 4; ++it) {
            const int ci = it * 512 + t;
            const int so = ((ci >> 7) << 12) | (kt << 11) | ((ci & 127) << 4);
            gld_lds16(bSrc + so, &lds[kt][32768 + ci * 16]);
        }
    }

    // tile0 ready (my oldest 8 loads done); barrier makes it block-wide.
    asm volatile("s_waitcnt vmcnt(8)" ::: "memory");
    __builtin_amdgcn_s_barrier();
    asm volatile("" ::: "memory");

#pragma unroll
    for (int kt = 0; kt < 2; ++kt) {
        if (kt == 1) {
            asm volatile("s_waitcnt vmcnt(0)" ::: "memory");
            __builtin_amdgcn_s_barrier();
            asm volatile("" ::: "memory");
        }
        const unsigned char* aL = &lds[kt][(wr * 8) * 2048] + lane * 16;
        const unsigned char* bL = &lds[kt][32768 + (wc * 4) * 2048] + lane * 16;
        OpU b8[4];
#pragma unroll
        for (int ni = 0; ni < 4; ++ni) {
            b8[ni].h[0] = *(const i32x4*)(bL + ni * 2048);
            b8[ni].h[1] = *(const i32x4*)(bL + ni * 2048 + 1024);
        }
#pragma unroll
        for (int mi = 0; mi < 8; ++mi) {
            OpU a8;
            a8.h[0] = *(const i32x4*)(aL + mi * 2048);
            a8.h[1] = *(const i32x4*)(aL + mi * 2048 + 1024);
#pragma unroll
            for (int ni = 0; ni < 4; ++ni)
                acc[mi][ni] = __builtin_amdgcn_mfma_scale_f32_16x16x128_f8f6f4(
                    a8.v, b8[ni].v, acc[mi][ni],
                    0, 0,                      // cbsz=FP8 e4m3, blgp=FP8 e4m3
                    0, 0x7F7F7F7F,             // opsel_a, scale_a = 1.0
                    0, 0x7F7F7F7F);            // opsel_b, scale_b = 1.0
        }
    }

    // ---- Epilogue ----
    // C frag layout: lane holds col = wc*64+ni*16+l15, row = wr*128+mi*16+quad*4+r.
    const float C2 = TEMP_INV * 1.44269504088896f;
    union RV { frag_cd v[4]; float f[16]; };
    RV r0, r1;
    frag_cd cv4[4];
#pragma unroll
    for (int i = 0; i < 4; ++i) {
        r0.v[i] = (frag_cd){0.0f, 0.0f, 0.0f, 0.0f};
        r1.v[i] = (frag_cd){0.0f, 0.0f, 0.0f, 0.0f};
        cv4[i]  = (frag_cd){0.0f, 0.0f, 0.0f, 0.0f};
    }
#pragma unroll
    for (int mi = 0; mi < 8; ++mi)
#pragma unroll
        for (int ni = 0; ni < 4; ++ni) {
            const frag_cd tt = acc[mi][ni] * C2 - C2;   // v_pk_fma_f32 x2
            frag_cd e;
#pragma unroll
            for (int rr = 0; rr < 4; ++rr) e[rr] = __builtin_amdgcn_exp2f(tt[rr]);
            if (mi < 4) r0.v[mi] += e; else r1.v[mi - 4] += e;
            cv4[ni] += e;
        }
    float cv[4];
#pragma unroll
    for (int ni = 0; ni < 4; ++ni)
        cv[ni] = (cv4[ni][0] + cv4[ni][1]) + (cv4[ni][2] + cv4[ni][3]);

    // Row butterfly all-reduce over 16 lanes of each quad; end: f[0] <-> p = l15.
#pragma unroll
    for (int s = 0; s < 4; ++s) {
        const bool bb = (l15 >> s) & 1;
#pragma unroll
        for (int i = 0; i < (8 >> s); ++i) {
            float a0 = r0.f[2 * i], a1 = r0.f[2 * i + 1];
            float keep = bb ? a1 : a0;
            float send = bb ? a0 : a1;
            r0.f[i] = keep + __shfl_xor(send, 1 << s);
            a0 = r1.f[2 * i]; a1 = r1.f[2 * i + 1];
            keep = bb ? a1 : a0;
            send = bb ? a0 : a1;
            r1.f[i] = keep + __shfl_xor(send, 1 << s);
        }
    }
    const int rbase = rowBase + wr * 128 + (l15 >> 2) * 16 + quad * 4 + (l15 & 3);
    atomicAdd(&row_sums[rbase],      r0.f[0]);
    atomicAdd(&row_sums[rbase + 64], r1.f[0]);

    // Col butterfly all-reduce over the 4 quads; end: cv[0] <-> ni = quad.
#pragma unroll
    for (int s = 0; s < 2; ++s) {
        const bool bb = (quad >> s) & 1;
#pragma unroll
        for (int i = 0; i < (2 >> s); ++i) {
            const float a0 = cv[2 * i], a1 = cv[2 * i + 1];
            const float keep = bb ? a1 : a0;
            const float send = bb ? a0 : a1;
            cv[i] = keep + __shfl_xor(send, 16 << s);
        }
    }
    atomicAdd(&col_sums[colBase + wc * 64 + quad * 16 + l15], cv[0]);
}

// Kernel 3 (parallel): each block reduces 256 rows, atomicAdd into zeroed out[0].
__global__ __launch_bounds__(256) void finalize_kernel(
    const float* __restrict__ rs, const float* __restrict__ cs,
    const float* __restrict__ dg, float* __restrict__ out) {
    const int i = blockIdx.x * 256 + threadIdx.x;
    float s = logf(rs[i]) + logf(cs[i]) - 2.0f * dg[i];
#pragma unroll
    for (int off = 32; off; off >>= 1) s += __shfl_down(s, off);
    __shared__ float buf[4];
    if ((threadIdx.x & 63) == 0) buf[threadIdx.x >> 6] = s;
    __syncthreads();
    if (threadIdx.x == 0) {
        float tot = (buf[0] + buf[1] + buf[2] + buf[3]) / (2.0f * B_ROWS);
        if (blockIdx.x == 0) tot += TEMP_INV;   // undo the fixed exp shift
        atomicAdd(out, tot);
    }
}

extern "C" void kernel_launch(void* const* d_in, const int* in_sizes, int n_in,
                              void* d_out, int out_size, void* d_ws, size_t ws_size,
                              hipStream_t stream) {
    const float* q = (const float*)d_in[0];
    const float* d = (const float*)d_in[1];
    float* out = (float*)d_out;

    char* ws = (char*)d_ws;
    unsigned char* qn = (unsigned char*)ws;                         // 4 MB fp8 (fragment-major)
    unsigned char* dn = qn + (size_t)B_ROWS * D_DIM;                // 4 MB fp8 (fragment-major)
    float* row_sums = (float*)(ws + 2 * (size_t)B_ROWS * D_DIM);
    float* col_sums = row_sums + B_ROWS;
    float* diag     = col_sums + B_ROWS;

    norm_diag_kernel<<<B_ROWS / 16, 256, 0, stream>>>(
        q, d, (unsigned int*)qn, (unsigned int*)dn, diag, row_sums, col_sums, out);
    gemm_lse_kernel<<<(B_ROWS / BM) * (B_ROWS / BN), 512, 0, stream>>>(
        qn, dn, row_sums, col_sums);
    finalize_kernel<<<B_ROWS / 256, 256, 0, stream>>>(row_sums, col_sums, diag, out);
}

// Round 3
// 163.629 us; speedup vs baseline: 1.2678x; 1.2678x over previous
//
#include <hip/hip_runtime.h>
#include <hip/hip_bf16.h>
#include <cstdint>
#include <cstddef>

#define B_ROWS 16384
#define D_DIM  256
#define TEMP_INV 14.285714285714286f   // 1/0.07

#define NITER 16      // 64-col iterations per block (chunk = 1024 cols)

using frag_cd = __attribute__((ext_vector_type(4))) float;   // 4 fp32
using i32x4   = __attribute__((ext_vector_type(4))) int;     // one 16B chunk
using i32x8   = __attribute__((ext_vector_type(8))) int;     // 32B f8f6f4 operand

// ---------------------------------------------------------------------------
// fp8 operand storage layout (R17, verified absmax=0): fragment-major.
// row group g = row>>4, r = row&15; k-byte kappa: kt = kappa>>7,
// chunk c = (kappa&127)>>4, h = c>>2, q = c&3, b = kappa&15.
// byte offset = g*4096 + kt*2048 + h*1024 + q*256 + r*16 + b.
// MFMA 16x16x128 fp8 fragment for lane (quad,l15): chunks c=quad (h0) and
// c=quad+4 (h1) of row l15's kt-slab == slab_base + lane*16 (+1024).
// => every fragment load is one contiguous 1KB wave load (global_load_dwordx4).
// ---------------------------------------------------------------------------

// Kernel 1 (R18, verified): one block per 16-row group; 16 lanes/row norms,
// fragment-major fp8 pack via small LDS buffer, coalesced uint4 stores.
// Also zero-initializes row_sums/col_sums/out.
__global__ __launch_bounds__(256) void norm_diag_kernel(
    const float* __restrict__ q, const float* __restrict__ d,
    unsigned int* __restrict__ qn, unsigned int* __restrict__ dn,
    float* __restrict__ diag,
    float* __restrict__ row_sums, float* __restrict__ col_sums,
    float* __restrict__ out) {
    const int b = blockIdx.x;   // group index, 0..1023
    if (b < 64)            row_sums[b * 256 + threadIdx.x] = 0.0f;
    else if (b < 128)      col_sums[(b - 64) * 256 + threadIdx.x] = 0.0f;
    else if (b == 128 && threadIdx.x == 0) out[0] = 0.0f;

    const int t    = threadIdx.x;
    const int lane = t & 63;
    const int w    = t >> 6;
    const int l15  = lane & 15;
    const int rw   = lane >> 4;          // row within wave's 4
    const int r    = w * 4 + rw;         // row & 15 (0..15)
    const int row  = b * 16 + r;

    const float4* qr = (const float4*)(q + (size_t)row * D_DIM);
    const float4* dr = (const float4*)(d + (size_t)row * D_DIM);
    float4 qv[4], dv[4];
    float qss = 0.f, dss = 0.f, qd = 0.f;
#pragma unroll
    for (int p = 0; p < 4; ++p) {
        qv[p] = qr[l15 + 16 * p];
        dv[p] = dr[l15 + 16 * p];
        qss += qv[p].x*qv[p].x + qv[p].y*qv[p].y + qv[p].z*qv[p].z + qv[p].w*qv[p].w;
        dss += dv[p].x*dv[p].x + dv[p].y*dv[p].y + dv[p].z*dv[p].z + dv[p].w*dv[p].w;
        qd  += qv[p].x*dv[p].x + qv[p].y*dv[p].y + qv[p].z*dv[p].z + qv[p].w*dv[p].w;
    }
#pragma unroll
    for (int off = 1; off < 16; off <<= 1) {
        qss += __shfl_xor(qss, off);
        dss += __shfl_xor(dss, off);
        qd  += __shfl_xor(qd,  off);
    }
    const float qinv = 1.0f / fmaxf(sqrtf(qss), 1e-12f);
    const float dinv = 1.0f / fmaxf(sqrtf(dss), 1e-12f);

    __shared__ unsigned int qbuf[1024], dbuf[1024];
#pragma unroll
    for (int p = 0; p < 4; ++p) {
        const int jw = l15 + 16 * p;     // word index in row, 0..63 (kappa=4*jw)
        int qp = 0, dp = 0;
        qp = __builtin_amdgcn_cvt_pk_fp8_f32(qv[p].x * qinv, qv[p].y * qinv, qp, false);
        qp = __builtin_amdgcn_cvt_pk_fp8_f32(qv[p].z * qinv, qv[p].w * qinv, qp, true);
        dp = __builtin_amdgcn_cvt_pk_fp8_f32(dv[p].x * dinv, dv[p].y * dinv, dp, false);
        dp = __builtin_amdgcn_cvt_pk_fp8_f32(dv[p].z * dinv, dv[p].w * dinv, dp, true);
        const int c    = (jw & 31) >> 2;
        const int widx = ((jw >> 5) << 9) | ((c >> 2) << 8) | ((c & 3) << 6)
                       | (r << 2) | (jw & 3);
        qbuf[widx] = (unsigned int)qp;
        dbuf[widx] = (unsigned int)dp;
    }
    if (l15 == 0) diag[row] = qd * qinv * dinv * TEMP_INV;
    __syncthreads();
    ((uint4*)qn)[(size_t)b * 256 + t] = ((const uint4*)qbuf)[t];
    ((uint4*)dn)[(size_t)b * 256 + t] = ((const uint4*)dbuf)[t];
}

// Kernel 2 (R19): column-streaming, A-in-registers, NO LDS, NO barriers.
// Block = 256 rows (4 waves x 64 rows); each wave holds its full 64x256 A-panel
// in 64 VGPRs (loaded once) and streams 16 iterations of 64 columns, loading
// only B fragments global->VGPR (fragment-major => contiguous 1KB wave loads,
// L2-resident: 512KB B working set per XCD via grid swizzle). kt-phase register
// double-buffer (bC/bN) gives ~550+ cycle prefetch distance over L2's ~300.
// Rationale: R16 was LDS-pipe bound (1 ds_read_b128/MFMA = 1.4x oversubscribed);
// R18 fixed the ratio but killed occupancy. Here LDS traffic is ZERO, waves are
// barrier-free (self-staggering), and A is never re-delivered.
__global__ __launch_bounds__(256, 2) void gemm_lse_kernel(
    const unsigned char* __restrict__ qn, const unsigned char* __restrict__ dn,
    float* __restrict__ row_sums, float* __restrict__ col_sums) {
    const int t    = threadIdx.x;
    const int lane = t & 63;
    const int w    = t >> 6;          // 0..3 : which 64-row strip
    const int l15  = lane & 15;
    const int quad = lane >> 4;

    // Grid: 1024 blocks = 64 row-groups x 16 col-chunks; 2 chunks per XCD so
    // each XCD's L2 holds only 512KB of B.
    const int id   = blockIdx.x;
    const int xcd  = id & 7;
    const int i    = id >> 3;               // 0..127
    const int chunk   = (xcd << 1) | (i & 1);   // 0..15
    const int rowg    = i >> 1;                 // 0..63
    const int rowBase = rowg * 256;
    const int colChunkBase = chunk * 1024;

    union OpU { i32x8 v; i32x4 h[2]; };

    // ---- Persistent A: 8 frags (4 mi x 2 kt) = 64 VGPRs, 16 coalesced loads.
    const unsigned char* aB = qn + ((size_t)((rowBase >> 4) + w * 4) << 12) + lane * 16;
    OpU a8[4][2];
#pragma unroll
    for (int mi = 0; mi < 4; ++mi)
#pragma unroll
        for (int kt = 0; kt < 2; ++kt) {
            a8[mi][kt].h[0] = *(const i32x4*)(aB + mi * 4096 + kt * 2048);
            a8[mi][kt].h[1] = *(const i32x4*)(aB + mi * 4096 + kt * 2048 + 1024);
        }

    // ---- B stream base; iter it, frag ni, half kt: bBase + it*16384 + ni*4096 + kt*2048.
    const unsigned char* bBase = dn + ((size_t)(colChunkBase >> 4) << 12) + lane * 16;

    OpU bC[4], bN[4];
#pragma unroll
    for (int ni = 0; ni < 4; ++ni) {         // preload iter0 kt0
        bC[ni].h[0] = *(const i32x4*)(bBase + ni * 4096);
        bC[ni].h[1] = *(const i32x4*)(bBase + ni * 4096 + 1024);
    }

    union RV { frag_cd v[4]; float f[16]; } rvu;   // per-row exp-sum accumulators
#pragma unroll
    for (int k = 0; k < 4; ++k) rvu.v[k] = (frag_cd){0.f, 0.f, 0.f, 0.f};

    const float C2 = TEMP_INV * 1.44269504088896f;

    for (int it = 0; it < NITER; ++it) {
        const unsigned char* bI = bBase + (size_t)it * 16384;

        // prefetch kt1 of this iter
#pragma unroll
        for (int ni = 0; ni < 4; ++ni) {
            bN[ni].h[0] = *(const i32x4*)(bI + ni * 4096 + 2048);
            bN[ni].h[1] = *(const i32x4*)(bI + ni * 4096 + 2048 + 1024);
        }

        frag_cd acc[4][4];
#pragma unroll
        for (int mi = 0; mi < 4; ++mi)
#pragma unroll
            for (int ni = 0; ni < 4; ++ni)
                acc[mi][ni] = (frag_cd){0.f, 0.f, 0.f, 0.f};

        // kt0 MFMAs on bC (loaded last phase)
#pragma unroll
        for (int mi = 0; mi < 4; ++mi)
#pragma unroll
            for (int ni = 0; ni < 4; ++ni)
                acc[mi][ni] = __builtin_amdgcn_mfma_scale_f32_16x16x128_f8f6f4(
                    a8[mi][0].v, bC[ni].v, acc[mi][ni],
                    0, 0, 0, 0x7F7F7F7F, 0, 0x7F7F7F7F);

        // prefetch next iter's kt0 into bC (anti-dep on the MFMAs above)
        if (it != NITER - 1) {
            const unsigned char* bI2 = bI + 16384;
#pragma unroll
            for (int ni = 0; ni < 4; ++ni) {
                bC[ni].h[0] = *(const i32x4*)(bI2 + ni * 4096);
                bC[ni].h[1] = *(const i32x4*)(bI2 + ni * 4096 + 1024);
            }
        }

        // kt1 MFMAs on bN
#pragma unroll
        for (int mi = 0; mi < 4; ++mi)
#pragma unroll
            for (int ni = 0; ni < 4; ++ni)
                acc[mi][ni] = __builtin_amdgcn_mfma_scale_f32_16x16x128_f8f6f4(
                    a8[mi][1].v, bN[ni].v, acc[mi][ni],
                    0, 0, 0, 0x7F7F7F7F, 0, 0x7F7F7F7F);

        // ---- per-iter epilogue ----
        // C frag layout: lane holds col = it*64 + ni*16 + l15,
        //                row = w*64 + mi*16 + quad*4 + r.
        frag_cd cv4[4];
#pragma unroll
        for (int k = 0; k < 4; ++k) cv4[k] = (frag_cd){0.f, 0.f, 0.f, 0.f};
#pragma unroll
        for (int mi = 0; mi < 4; ++mi)
#pragma unroll
            for (int ni = 0; ni < 4; ++ni) {
                const frag_cd tt = acc[mi][ni] * C2 - C2;   // v_pk_fma_f32 x2
                frag_cd e;
#pragma unroll
                for (int rr = 0; rr < 4; ++rr) e[rr] = __builtin_amdgcn_exp2f(tt[rr]);
                rvu.v[mi] += e;    // row partials accumulate across all iters
                cv4[ni]   += e;
            }
        float cv[4];
#pragma unroll
        for (int ni = 0; ni < 4; ++ni)
            cv[ni] = (cv4[ni][0] + cv4[ni][1]) + (cv4[ni][2] + cv4[ni][3]);

        // col butterfly over the 4 quads; end: cv[0] <-> ni = quad
#pragma unroll
        for (int s = 0; s < 2; ++s) {
            const bool bb = (quad >> s) & 1;
#pragma unroll
            for (int k = 0; k < (2 >> s); ++k) {
                const float a0 = cv[2 * k], a1 = cv[2 * k + 1];
                const float keep = bb ? a1 : a0;
                const float send = bb ? a0 : a1;
                cv[k] = keep + __shfl_xor(send, 16 << s);
            }
        }
        atomicAdd(&col_sums[colChunkBase + it * 64 + quad * 16 + l15], cv[0]);
    }

    // ---- final row butterfly all-reduce over the 16 lanes of each quad ----
#pragma unroll
    for (int s = 0; s < 4; ++s) {
        const bool bb = (l15 >> s) & 1;
#pragma unroll
        for (int k = 0; k < (8 >> s); ++k) {
            const float a0 = rvu.f[2 * k], a1 = rvu.f[2 * k + 1];
            const float keep = bb ? a1 : a0;
            const float send = bb ? a0 : a1;
            rvu.f[k] = keep + __shfl_xor(send, 1 << s);
        }
    }
    atomicAdd(&row_sums[rowBase + w * 64 + (l15 >> 2) * 16 + quad * 4 + (l15 & 3)],
              rvu.f[0]);
}

// Kernel 3 (parallel): each block reduces 256 rows, atomicAdd into zeroed out[0].
__global__ __launch_bounds__(256) void finalize_kernel(
    const float* __restrict__ rs, const float* __restrict__ cs,
    const float* __restrict__ dg, float* __restrict__ out) {
    const int i = blockIdx.x * 256 + threadIdx.x;
    float s = logf(rs[i]) + logf(cs[i]) - 2.0f * dg[i];
#pragma unroll
    for (int off = 32; off; off >>= 1) s += __shfl_down(s, off);
    __shared__ float buf[4];
    if ((threadIdx.x & 63) == 0) buf[threadIdx.x >> 6] = s;
    __syncthreads();
    if (threadIdx.x == 0) {
        float tot = (buf[0] + buf[1] + buf[2] + buf[3]) / (2.0f * B_ROWS);
        if (blockIdx.x == 0) tot += TEMP_INV;   // undo the fixed exp shift
        atomicAdd(out, tot);
    }
}

extern "C" void kernel_launch(void* const* d_in, const int* in_sizes, int n_in,
                              void* d_out, int out_size, void* d_ws, size_t ws_size,
                              hipStream_t stream) {
    const float* q = (const float*)d_in[0];
    const float* d = (const float*)d_in[1];
    float* out = (float*)d_out;

    char* ws = (char*)d_ws;
    unsigned char* qn = (unsigned char*)ws;                         // 4 MB fp8 (fragment-major)
    unsigned char* dn = qn + (size_t)B_ROWS * D_DIM;                // 4 MB fp8 (fragment-major)
    float* row_sums = (float*)(ws + 2 * (size_t)B_ROWS * D_DIM);
    float* col_sums = row_sums + B_ROWS;
    float* diag     = col_sums + B_ROWS;

    norm_diag_kernel<<<B_ROWS / 16, 256, 0, stream>>>(
        q, d, (unsigned int*)qn, (unsigned int*)dn, diag, row_sums, col_sums, out);
    gemm_lse_kernel<<<(B_ROWS / 256) * (B_ROWS / 1024), 256, 0, stream>>>(
        qn, dn, row_sums, col_sums);
    finalize_kernel<<<B_ROWS / 256, 256, 0, stream>>>(row_sums, col_sums, diag, out);
}

// Round 4
// 149.787 us; speedup vs baseline: 1.3849x; 1.0924x over previous
//
#include <hip/hip_runtime.h>
#include <hip/hip_bf16.h>
#include <cstdint>
#include <cstddef>

#define B_ROWS 16384
#define D_DIM  256
#define TEMP_INV 14.285714285714286f   // 1/0.07

#define NITER 16      // 64-col iterations per block (chunk = 1024 cols)

using frag_cd = __attribute__((ext_vector_type(4))) float;   // 4 fp32
using i32x4   = __attribute__((ext_vector_type(4))) int;     // one 16B chunk
using i32x8   = __attribute__((ext_vector_type(8))) int;     // 32B f8f6f4 operand

__device__ __forceinline__ void gld_lds16(const void* g, void* l) {
    __builtin_amdgcn_global_load_lds(
        (const __attribute__((address_space(1))) void*)g,
        (__attribute__((address_space(3))) void*)l,
        16, 0, 0);
}

// ---------------------------------------------------------------------------
// fp8 operand storage layout (R17, verified absmax=0): fragment-major.
// row group g = row>>4, r = row&15; k-byte kappa: kt = kappa>>7,
// chunk c = (kappa&127)>>4, h = c>>2, q = c&3, b = kappa&15.
// byte offset = g*4096 + kt*2048 + h*1024 + q*256 + r*16 + b.
// MFMA 16x16x128 fp8 fragment for lane (quad,l15): chunks c=quad (h0) and
// c=quad+4 (h1) of row l15's kt-slab == slab_base + lane*16 (+1024).
// => fragment load = one contiguous 1KB wave load; 64-col slab = 16KB linear.
// ---------------------------------------------------------------------------

// Kernel 1 (R18, verified): one block per 16-row group; 16 lanes/row norms,
// fragment-major fp8 pack via small LDS buffer, coalesced uint4 stores.
// Also zero-initializes row_sums/col_sums/out.
__global__ __launch_bounds__(256) void norm_diag_kernel(
    const float* __restrict__ q, const float* __restrict__ d,
    unsigned int* __restrict__ qn, unsigned int* __restrict__ dn,
    float* __restrict__ diag,
    float* __restrict__ row_sums, float* __restrict__ col_sums,
    float* __restrict__ out) {
    const int b = blockIdx.x;   // group index, 0..1023
    if (b < 64)            row_sums[b * 256 + threadIdx.x] = 0.0f;
    else if (b < 128)      col_sums[(b - 64) * 256 + threadIdx.x] = 0.0f;
    else if (b == 128 && threadIdx.x == 0) out[0] = 0.0f;

    const int t    = threadIdx.x;
    const int lane = t & 63;
    const int w    = t >> 6;
    const int l15  = lane & 15;
    const int rw   = lane >> 4;          // row within wave's 4
    const int r    = w * 4 + rw;         // row & 15 (0..15)
    const int row  = b * 16 + r;

    const float4* qr = (const float4*)(q + (size_t)row * D_DIM);
    const float4* dr = (const float4*)(d + (size_t)row * D_DIM);
    float4 qv[4], dv[4];
    float qss = 0.f, dss = 0.f, qd = 0.f;
#pragma unroll
    for (int p = 0; p < 4; ++p) {
        qv[p] = qr[l15 + 16 * p];
        dv[p] = dr[l15 + 16 * p];
        qss += qv[p].x*qv[p].x + qv[p].y*qv[p].y + qv[p].z*qv[p].z + qv[p].w*qv[p].w;
        dss += dv[p].x*dv[p].x + dv[p].y*dv[p].y + dv[p].z*dv[p].z + dv[p].w*dv[p].w;
        qd  += qv[p].x*dv[p].x + qv[p].y*dv[p].y + qv[p].z*dv[p].z + qv[p].w*dv[p].w;
    }
#pragma unroll
    for (int off = 1; off < 16; off <<= 1) {
        qss += __shfl_xor(qss, off);
        dss += __shfl_xor(dss, off);
        qd  += __shfl_xor(qd,  off);
    }
    const float qinv = 1.0f / fmaxf(sqrtf(qss), 1e-12f);
    const float dinv = 1.0f / fmaxf(sqrtf(dss), 1e-12f);

    __shared__ unsigned int qbuf[1024], dbuf[1024];
#pragma unroll
    for (int p = 0; p < 4; ++p) {
        const int jw = l15 + 16 * p;     // word index in row, 0..63 (kappa=4*jw)
        int qp = 0, dp = 0;
        qp = __builtin_amdgcn_cvt_pk_fp8_f32(qv[p].x * qinv, qv[p].y * qinv, qp, false);
        qp = __builtin_amdgcn_cvt_pk_fp8_f32(qv[p].z * qinv, qv[p].w * qinv, qp, true);
        dp = __builtin_amdgcn_cvt_pk_fp8_f32(dv[p].x * dinv, dv[p].y * dinv, dp, false);
        dp = __builtin_amdgcn_cvt_pk_fp8_f32(dv[p].z * dinv, dv[p].w * dinv, dp, true);
        const int c    = (jw & 31) >> 2;
        const int widx = ((jw >> 5) << 9) | ((c >> 2) << 8) | ((c & 3) << 6)
                       | (r << 2) | (jw & 3);
        qbuf[widx] = (unsigned int)qp;
        dbuf[widx] = (unsigned int)dp;
    }
    if (l15 == 0) diag[row] = qd * qinv * dinv * TEMP_INV;
    __syncthreads();
    ((uint4*)qn)[(size_t)b * 256 + t] = ((const uint4*)qbuf)[t];
    ((uint4*)dn)[(size_t)b * 256 + t] = ((const uint4*)dbuf)[t];
}

// Kernel 2 (R20): column-streaming, A-in-registers, B via LDS triple-buffer
// with counted vmcnt (T3/T4 minimum form) + setprio (T5).
// R19 post-mortem: VGPR=100 proved the compiler rematerialized the 240-reg
// live set -> L2 latency landed on the MFMA chain and lockstep waves couldn't
// hide it (MfmaUtil 27% == MFMA-floor/wall). Fix: B operands move to LDS
// (staged once per block via global_load_lds, zero VGPR cost, shared by all
// 4 waves -> B delivery drops 4x to 256MB); per-wave live set ~180 regs fits
// the 256-reg cap, so the A panel really stays resident. Pipeline: stage
// iter+2 while computing iter, ONE s_barrier/iter, steady-state vmcnt(4) --
// never 0 in the loop. ds_read:MFMA = 16:32 -> LDS pipe ~20us < MFMA 29.5us.
__global__ __launch_bounds__(256, 2) void gemm_lse_kernel(
    const unsigned char* __restrict__ qn, const unsigned char* __restrict__ dn,
    float* __restrict__ row_sums, float* __restrict__ col_sums) {
    __shared__ unsigned char ldsB[3][16384];   // 48 KB: 3 x (64 cols x 256 K)

    const int t    = threadIdx.x;
    const int lane = t & 63;
    const int w    = t >> 6;          // 0..3 : which 64-row strip
    const int l15  = lane & 15;
    const int quad = lane >> 4;

    // Grid: 1024 blocks = 64 row-groups x 16 col-chunks; 2 chunks per XCD.
    const int id   = blockIdx.x;
    const int xcd  = id & 7;
    const int i    = id >> 3;               // 0..127
    const int chunk   = (xcd << 1) | (i & 1);   // 0..15
    const int rowg    = i >> 1;                 // 0..63
    const int rowBase = rowg * 256;
    const int colChunkBase = chunk * 1024;

    union OpU { i32x8 v; i32x4 h[2]; };

    // ---- Persistent A: 8 frags (4 mi x 2 kt) = 64 VGPRs, 16 coalesced loads.
    const unsigned char* aB = qn + ((size_t)((rowBase >> 4) + w * 4) << 12) + lane * 16;
    OpU a8[4][2];
#pragma unroll
    for (int mi = 0; mi < 4; ++mi)
#pragma unroll
        for (int kt = 0; kt < 2; ++kt) {
            a8[mi][kt].h[0] = *(const i32x4*)(aB + mi * 4096 + kt * 2048);
            a8[mi][kt].h[1] = *(const i32x4*)(aB + mi * 4096 + kt * 2048 + 1024);
        }

    // ---- B stream: iter it occupies 16KB linear slab at bG + it*16384.
    const unsigned char* bG = dn + ((size_t)(colChunkBase >> 4) << 12);

    // Stage iter j -> buffer buf (16KB linear copy; LDS dest = uniform base
    // + lane*16 as required by global_load_lds).
    // 4 loads/thread; each stage call adds 4 to this thread's vmcnt.
#define STAGE(bufidx, j)                                                      \
    {                                                                          \
        const unsigned char* gsrc = bG + (size_t)(j) * 16384;                  \
        unsigned char* ldst = &ldsB[bufidx][0];                                \
        _Pragma("unroll")                                                      \
        for (int ii = 0; ii < 4; ++ii)                                         \
            gld_lds16(gsrc + ii * 4096 + t * 16, ldst + ii * 4096 + t * 16);   \
    }

    // Prologue: stage iters 0 and 1 (8 loads in flight per thread).
    STAGE(0, 0)
    STAGE(1, 1)

    union RV { frag_cd v[4]; float f[16]; } rvu;   // per-row exp-sum accumulators
#pragma unroll
    for (int k = 0; k < 4; ++k) rvu.v[k] = (frag_cd){0.f, 0.f, 0.f, 0.f};

    const float C2 = TEMP_INV * 1.44269504088896f;

    int cur = 0;   // buffer holding iter it
#pragma unroll 1
    for (int it = 0; it < NITER; ++it) {
        // Wait for iter it's 4 loads (leave later stages in flight); barrier
        // doubles as "all waves finished iter it-1" (overwrite safety).
        if (it == NITER - 1) asm volatile("s_waitcnt vmcnt(0)" ::: "memory");
        else                 asm volatile("s_waitcnt vmcnt(4)" ::: "memory");
        __builtin_amdgcn_s_barrier();
        asm volatile("" ::: "memory");

        // Stage iter it+2 into the buffer freed at iter it-1.
        const int nxt = (cur + 2 >= 3) ? cur - 1 : cur + 2;
        if (it + 2 < NITER) STAGE(nxt, it + 2)

        const unsigned char* bL = &ldsB[cur][0] + lane * 16;

        frag_cd acc[4][4];
#pragma unroll
        for (int mi = 0; mi < 4; ++mi)
#pragma unroll
            for (int ni = 0; ni < 4; ++ni)
                acc[mi][ni] = (frag_cd){0.f, 0.f, 0.f, 0.f};

        // kt0: 4 B frags from LDS, 16 MFMA
        {
            OpU b8[4];
#pragma unroll
            for (int ni = 0; ni < 4; ++ni) {
                b8[ni].h[0] = *(const i32x4*)(bL + ni * 4096);
                b8[ni].h[1] = *(const i32x4*)(bL + ni * 4096 + 1024);
            }
            __builtin_amdgcn_s_setprio(1);
#pragma unroll
            for (int mi = 0; mi < 4; ++mi)
#pragma unroll
                for (int ni = 0; ni < 4; ++ni)
                    acc[mi][ni] = __builtin_amdgcn_mfma_scale_f32_16x16x128_f8f6f4(
                        a8[mi][0].v, b8[ni].v, acc[mi][ni],
                        0, 0, 0, 0x7F7F7F7F, 0, 0x7F7F7F7F);
            __builtin_amdgcn_s_setprio(0);
        }
        // kt1: 4 B frags, 16 MFMA
        {
            OpU b8[4];
#pragma unroll
            for (int ni = 0; ni < 4; ++ni) {
                b8[ni].h[0] = *(const i32x4*)(bL + ni * 4096 + 2048);
                b8[ni].h[1] = *(const i32x4*)(bL + ni * 4096 + 2048 + 1024);
            }
            __builtin_amdgcn_s_setprio(1);
#pragma unroll
            for (int mi = 0; mi < 4; ++mi)
#pragma unroll
                for (int ni = 0; ni < 4; ++ni)
                    acc[mi][ni] = __builtin_amdgcn_mfma_scale_f32_16x16x128_f8f6f4(
                        a8[mi][1].v, b8[ni].v, acc[mi][ni],
                        0, 0, 0, 0x7F7F7F7F, 0, 0x7F7F7F7F);
            __builtin_amdgcn_s_setprio(0);
        }

        // ---- per-iter epilogue ----
        // C frag layout: lane holds col = colChunkBase + it*64 + ni*16 + l15,
        //                row = rowBase + w*64 + mi*16 + quad*4 + r.
        frag_cd cv4[4];
#pragma unroll
        for (int k = 0; k < 4; ++k) cv4[k] = (frag_cd){0.f, 0.f, 0.f, 0.f};
#pragma unroll
        for (int mi = 0; mi < 4; ++mi)
#pragma unroll
            for (int ni = 0; ni < 4; ++ni) {
                const frag_cd tt = acc[mi][ni] * C2 - C2;   // v_pk_fma_f32 x2
                frag_cd e;
#pragma unroll
                for (int rr = 0; rr < 4; ++rr) e[rr] = __builtin_amdgcn_exp2f(tt[rr]);
                rvu.v[mi] += e;    // row partials accumulate across all iters
                cv4[ni]   += e;
            }
        float cv[4];
#pragma unroll
        for (int ni = 0; ni < 4; ++ni)
            cv[ni] = (cv4[ni][0] + cv4[ni][1]) + (cv4[ni][2] + cv4[ni][3]);

        // col butterfly over the 4 quads; end: cv[0] <-> ni = quad
#pragma unroll
        for (int s = 0; s < 2; ++s) {
            const bool bb = (quad >> s) & 1;
#pragma unroll
            for (int k = 0; k < (2 >> s); ++k) {
                const float a0 = cv[2 * k], a1 = cv[2 * k + 1];
                const float keep = bb ? a1 : a0;
                const float send = bb ? a0 : a1;
                cv[k] = keep + __shfl_xor(send, 16 << s);
            }
        }
        atomicAdd(&col_sums[colChunkBase + it * 64 + quad * 16 + l15], cv[0]);

        cur = (cur + 1 >= 3) ? 0 : cur + 1;
    }
#undef STAGE

    // ---- final row butterfly all-reduce over the 16 lanes of each quad ----
#pragma unroll
    for (int s = 0; s < 4; ++s) {
        const bool bb = (l15 >> s) & 1;
#pragma unroll
        for (int k = 0; k < (8 >> s); ++k) {
            const float a0 = rvu.f[2 * k], a1 = rvu.f[2 * k + 1];
            const float keep = bb ? a1 : a0;
            const float send = bb ? a0 : a1;
            rvu.f[k] = keep + __shfl_xor(send, 1 << s);
        }
    }
    atomicAdd(&row_sums[rowBase + w * 64 + (l15 >> 2) * 16 + quad * 4 + (l15 & 3)],
              rvu.f[0]);
}

// Kernel 3 (parallel): each block reduces 256 rows, atomicAdd into zeroed out[0].
__global__ __launch_bounds__(256) void finalize_kernel(
    const float* __restrict__ rs, const float* __restrict__ cs,
    const float* __restrict__ dg, float* __restrict__ out) {
    const int i = blockIdx.x * 256 + threadIdx.x;
    float s = logf(rs[i]) + logf(cs[i]) - 2.0f * dg[i];
#pragma unroll
    for (int off = 32; off; off >>= 1) s += __shfl_down(s, off);
    __shared__ float buf[4];
    if ((threadIdx.x & 63) == 0) buf[threadIdx.x >> 6] = s;
    __syncthreads();
    if (threadIdx.x == 0) {
        float tot = (buf[0] + buf[1] + buf[2] + buf[3]) / (2.0f * B_ROWS);
        if (blockIdx.x == 0) tot += TEMP_INV;   // undo the fixed exp shift
        atomicAdd(out, tot);
    }
}

extern "C" void kernel_launch(void* const* d_in, const int* in_sizes, int n_in,
                              void* d_out, int out_size, void* d_ws, size_t ws_size,
                              hipStream_t stream) {
    const float* q = (const float*)d_in[0];
    const float* d = (const float*)d_in[1];
    float* out = (float*)d_out;

    char* ws = (char*)d_ws;
    unsigned char* qn = (unsigned char*)ws;                         // 4 MB fp8 (fragment-major)
    unsigned char* dn = qn + (size_t)B_ROWS * D_DIM;                // 4 MB fp8 (fragment-major)
    float* row_sums = (float*)(ws + 2 * (size_t)B_ROWS * D_DIM);
    float* col_sums = row_sums + B_ROWS;
    float* diag     = col_sums + B_ROWS;

    norm_diag_kernel<<<B_ROWS / 16, 256, 0, stream>>>(
        q, d, (unsigned int*)qn, (unsigned int*)dn, diag, row_sums, col_sums, out);
    gemm_lse_kernel<<<(B_ROWS / 256) * (B_ROWS / 1024), 256, 0, stream>>>(
        qn, dn, row_sums, col_sums);
    finalize_kernel<<<B_ROWS / 256, 256, 0, stream>>>(row_sums, col_sums, diag, out);
}